// Round 19
// baseline (370.536 us; speedup 1.0000x reference)
//
#include <hip/hip_runtime.h>
#include <hip/hip_fp16.h>
#include <math.h>

// ---------------------------------------------------------------------------
// TopoPoolNet: GCN(128->64) -> GCN(64->64) -> sigmoid score gate ->
//              per-graph max||mean pool -> MLP(128->64->2)
//
// Round-18: agg is latency-exposure bound (FETCH 164MB @1.65TB/s, VALU 45%,
// occ 80% -- nothing saturated). Single change vs R17: a full 32-edge
// iteration (4 indep pack loads -> 4 indep dwordx4 row-gathers in flight)
// for deg>=32 nodes. No predication padding (R12 lesson: padded gathers
// inflate FETCH). Remainder uses the proven 16/8-edge paths.
// ---------------------------------------------------------------------------

#define TPN_BLK 256
#define P1_EPT  16                   // edges per thread in bin pass
#define P1_CHUNK (TPN_BLK * P1_EPT)  // 4096 edges per block
#define NB_MAX  512
#define BCAP    12288                // per-bin capacity (mean ~8184)

static __device__ __forceinline__ uint2 f4_to_h4(float4 v) {
    __half2 a = __floats2half2_rn(v.x, v.y);
    __half2 b = __floats2half2_rn(v.z, v.w);
    uint2 u;
    u.x = *reinterpret_cast<unsigned*>(&a);
    u.y = *reinterpret_cast<unsigned*>(&b);
    return u;
}

// ---- pass 1: block-level counting sort by bin (col>>8), coalesced out -----
__global__ __launch_bounds__(256)
void tpn_bin(const int* __restrict__ ei, const float* __restrict__ ew,
             int* __restrict__ binCur, uint2* __restrict__ binned,
             int E, int NB) {
    __shared__ uint2          sbuf[P1_CHUNK];      // 32 KB
    __shared__ unsigned short sbin[P1_CHUNK];      // 8 KB
    __shared__ int hist[NB_MAX];
    __shared__ int loff[NB_MAX];
    __shared__ int lrank[NB_MAX];
    __shared__ int gbase[NB_MAX];
    __shared__ int ssc[256];

    int tid = threadIdx.x;
    for (int b = tid; b < NB_MAX; b += 256) { hist[b] = 0; lrank[b] = 0; }
    __syncthreads();

    int base = blockIdx.x * P1_CHUNK;
    uint2 ed[P1_EPT];
    int   bn[P1_EPT];
    #pragma unroll
    for (int j = 0; j < P1_EPT; ++j) {
        int e = base + tid + j * 256;
        bn[j] = -1;
        if (e < E) {
            int r = ei[e], c = ei[E + e];
            bn[j] = c >> 8;
            ed[j] = make_uint2((unsigned)r | ((unsigned)(c & 255) << 17),
                               __float_as_uint(ew[e]));
            atomicAdd(&hist[bn[j]], 1);
        }
    }
    __syncthreads();
    {
        int b0 = 2 * tid, b1 = 2 * tid + 1;
        int h0 = hist[b0], h1 = hist[b1];
        int s = h0 + h1;
        ssc[tid] = s;
        __syncthreads();
        for (int st = 1; st < 256; st <<= 1) {
            int v = (tid >= st) ? ssc[tid - st] : 0;
            __syncthreads();
            ssc[tid] += v;
            __syncthreads();
        }
        int pre = ssc[tid] - s;
        loff[b0] = pre;
        loff[b1] = pre + h0;
    }
    __syncthreads();
    for (int b = tid; b < NB; b += 256) {
        int h = hist[b];
        if (h > 0) gbase[b] = atomicAdd(&binCur[b], h);
    }
    #pragma unroll
    for (int j = 0; j < P1_EPT; ++j) {
        if (bn[j] >= 0) {
            int p = loff[bn[j]] + atomicAdd(&lrank[bn[j]], 1);
            sbuf[p] = ed[j];
            sbin[p] = (unsigned short)bn[j];
        }
    }
    __syncthreads();
    int m = min(E - base, P1_CHUNK);
    for (int i = tid; i < m; i += 256) {
        uint2 u = sbuf[i];
        int b = sbin[i];
        int dst = gbase[b] + (i - loff[b]);
        if (dst < BCAP) binned[(size_t)b * BCAP + dst] = u;
    }
}

// ---- exclusive scan of bin counts (single block) ---------------------------
__global__ void tpn_binscan(const int* __restrict__ binCur, int* __restrict__ binOff,
                            int NB) {
    __shared__ int sh[NB_MAX];
    int t = threadIdx.x;
    int v = (t < NB) ? min(binCur[t], BCAP) : 0;
    sh[t] = v;
    __syncthreads();
    for (int st = 1; st < NB_MAX; st <<= 1) {
        int u = (t >= st) ? sh[t - st] : 0;
        __syncthreads();
        sh[t] += u;
        __syncthreads();
    }
    if (t < NB) binOff[t] = sh[t] - v;
}

// ---- pass 2: per-bin packed CSR build + dis --------------------------------
__global__ void tpn_build(const uint2* __restrict__ binned, const int* __restrict__ binCur,
                          const int* __restrict__ binOff, uint2* __restrict__ packed,
                          int* __restrict__ off, int* __restrict__ cnt,
                          float* __restrict__ dis, int N) {
    __shared__ int   lcnt[256];
    __shared__ int   loff[256];
    __shared__ int   lrank[256];
    __shared__ int   lincl[256];
    __shared__ float ldeg[256];
    int b = blockIdx.x, tid = threadIdx.x;
    int m = min(binCur[b], BCAP);
    const uint2* src = binned + (size_t)b * BCAP;
    lcnt[tid] = 0; lrank[tid] = 0; ldeg[tid] = 0.0f;
    __syncthreads();
    for (int i = tid; i < m; i += 256) {
        uint2 u = src[i];
        int ln = u.x >> 17;
        atomicAdd(&lcnt[ln], 1);
        atomicAdd(&ldeg[ln], __uint_as_float(u.y));
    }
    __syncthreads();
    lincl[tid] = lcnt[tid];
    __syncthreads();
    for (int st = 1; st < 256; st <<= 1) {
        int u = (tid >= st) ? lincl[tid - st] : 0;
        __syncthreads();
        lincl[tid] += u;
        __syncthreads();
    }
    int excl = lincl[tid] - lcnt[tid];
    loff[tid] = excl;
    int node = (b << 8) + tid;
    if (node < N) {
        off[node] = binOff[b] + excl;
        cnt[node] = lcnt[tid];
        float s = ldeg[tid];
        dis[node] = (s > 0.0f) ? rsqrtf(fmaxf(s, 1e-12f)) : 0.0f;
    }
    __syncthreads();
    int gbase = binOff[b];
    for (int i = tid; i < m; i += 256) {
        uint2 u = src[i];
        int ln = u.x >> 17;
        int rk = atomicAdd(&lrank[ln], 1);
        packed[gbase + loff[ln] + rk] = make_uint2(u.x & 0x1FFFF, u.y);
    }
}

// ---- tiled GEMM: Y[n,f] = fp16(dis[n] * sum_k X[n,k]*W[k,f]); 64x64 tile ---
__global__ __launch_bounds__(256, 4)
void tpn_gemm_t(const float* __restrict__ X, const float* __restrict__ W,
                const float* __restrict__ dis, __half* __restrict__ Y,
                int N, int K) {
    __shared__ float sX[64][68];
    __shared__ float sW[64][64];
    const int t  = threadIdx.x;
    const int r  = t >> 4;
    const int cc = t & 15;
    const int fg = t & 15;
    const int ng = t >> 4;
    const int nb = blockIdx.x * 64;

    float acc[4][4] = {{0.f}};

    for (int kc = 0; kc < K; kc += 64) {
        __syncthreads();
        #pragma unroll
        for (int p = 0; p < 4; ++p) {
            int n = nb + r + p * 16;
            int ns = (n < N) ? n : (N - 1);
            float4 v = *reinterpret_cast<const float4*>(X + (size_t)ns * K + kc + 4 * cc);
            *reinterpret_cast<float4*>(&sX[r + p * 16][4 * cc]) = v;
        }
        #pragma unroll
        for (int p = 0; p < 4; ++p) {
            int k = kc + r + p * 16;
            float4 v = *reinterpret_cast<const float4*>(W + (size_t)k * 64 + 4 * cc);
            *reinterpret_cast<float4*>(&sW[r + p * 16][4 * cc]) = v;
        }
        __syncthreads();
        #pragma unroll 4
        for (int k = 0; k < 64; ++k) {
            float4 wv = *reinterpret_cast<const float4*>(&sW[k][4 * fg]);
            float x0 = sX[4 * ng + 0][k];
            float x1 = sX[4 * ng + 1][k];
            float x2 = sX[4 * ng + 2][k];
            float x3 = sX[4 * ng + 3][k];
            acc[0][0] = fmaf(x0, wv.x, acc[0][0]);
            acc[0][1] = fmaf(x0, wv.y, acc[0][1]);
            acc[0][2] = fmaf(x0, wv.z, acc[0][2]);
            acc[0][3] = fmaf(x0, wv.w, acc[0][3]);
            acc[1][0] = fmaf(x1, wv.x, acc[1][0]);
            acc[1][1] = fmaf(x1, wv.y, acc[1][1]);
            acc[1][2] = fmaf(x1, wv.z, acc[1][2]);
            acc[1][3] = fmaf(x1, wv.w, acc[1][3]);
            acc[2][0] = fmaf(x2, wv.x, acc[2][0]);
            acc[2][1] = fmaf(x2, wv.y, acc[2][1]);
            acc[2][2] = fmaf(x2, wv.z, acc[2][2]);
            acc[2][3] = fmaf(x2, wv.w, acc[2][3]);
            acc[3][0] = fmaf(x3, wv.x, acc[3][0]);
            acc[3][1] = fmaf(x3, wv.y, acc[3][1]);
            acc[3][2] = fmaf(x3, wv.z, acc[3][2]);
            acc[3][3] = fmaf(x3, wv.w, acc[3][3]);
        }
    }
    #pragma unroll
    for (int i = 0; i < 4; ++i) {
        int n = nb + 4 * ng + i;
        if (n < N) {
            float d = dis[n];
            float4 v = make_float4(acc[i][0] * d, acc[i][1] * d,
                                   acc[i][2] * d, acc[i][3] * d);
            *reinterpret_cast<uint2*>(Y + (size_t)n * 64 + 4 * fg) = f4_to_h4(v);
        }
    }
}

// ---- aggregate: wave/node, 8 lanes x dwordx4 (16B) per edge row ------------
// Full 32-edge iteration: 4 indep pack loads + 4 indep gathers in flight.
// Remainder: 16-edge (2-deep) then predicated 8-edge steps.
// FUSE_W2: epilogue computes Hout_row = fp16(dis[n] * (relu_row @ W2)).
// FUSE_SCORE: sigmoid score gate (layer 2).
template <bool FUSE_SCORE, bool FUSE_W2>
__global__ __launch_bounds__(256)
void tpn_agg(const uint2* __restrict__ packed, const int* __restrict__ off,
             const int* __restrict__ cnt, const float* __restrict__ dis,
             const __half* __restrict__ Hin, const float* __restrict__ bias,
             const float* __restrict__ pw, const float* __restrict__ pb,
             const float* __restrict__ W2, __half* __restrict__ Hout, int N) {
    int wid = (blockIdx.x * blockDim.x + threadIdx.x) >> 6;
    int lane = threadIdx.x & 63;
    if (wid >= N) return;
    const int eg = lane >> 3;        // edge slot 0..7
    const int fb = (lane & 7) * 8;   // feature base: fb..fb+7 (8 fp16 = 16B)
    int start = off[wid], n = cnt[wid];
    const uint2* b = packed + start;
    const __half* hp = Hin + fb;
    float dc = dis[wid];

    float A0[8], A1[8], A2[8], A3[8];
    #pragma unroll
    for (int i = 0; i < 8; ++i) { A0[i] = 0.f; A1[i] = 0.f; A2[i] = 0.f; A3[i] = 0.f; }

    int j = 0;
    // full 32-edge iterations: 4 independent pack+gather chains in flight
    for (; j + 32 <= n; j += 32) {
        uint2 p0 = b[j + eg];
        uint2 p1 = b[j + 8 + eg];
        uint2 p2 = b[j + 16 + eg];
        uint2 p3 = b[j + 24 + eg];
        uint4 r0 = *reinterpret_cast<const uint4*>(hp + (size_t)p0.x * 64);
        uint4 r1 = *reinterpret_cast<const uint4*>(hp + (size_t)p1.x * 64);
        uint4 r2 = *reinterpret_cast<const uint4*>(hp + (size_t)p2.x * 64);
        uint4 r3 = *reinterpret_cast<const uint4*>(hp + (size_t)p3.x * 64);
        float w0 = __uint_as_float(p0.y);
        float w1 = __uint_as_float(p1.y);
        float w2 = __uint_as_float(p2.y);
        float w3 = __uint_as_float(p3.y);
        {
            float2 a = __half22float2(*reinterpret_cast<__half2*>(&r0.x));
            float2 c = __half22float2(*reinterpret_cast<__half2*>(&r0.y));
            float2 d = __half22float2(*reinterpret_cast<__half2*>(&r0.z));
            float2 e = __half22float2(*reinterpret_cast<__half2*>(&r0.w));
            A0[0] = fmaf(w0, a.x, A0[0]); A0[1] = fmaf(w0, a.y, A0[1]);
            A0[2] = fmaf(w0, c.x, A0[2]); A0[3] = fmaf(w0, c.y, A0[3]);
            A0[4] = fmaf(w0, d.x, A0[4]); A0[5] = fmaf(w0, d.y, A0[5]);
            A0[6] = fmaf(w0, e.x, A0[6]); A0[7] = fmaf(w0, e.y, A0[7]);
        }
        {
            float2 a = __half22float2(*reinterpret_cast<__half2*>(&r1.x));
            float2 c = __half22float2(*reinterpret_cast<__half2*>(&r1.y));
            float2 d = __half22float2(*reinterpret_cast<__half2*>(&r1.z));
            float2 e = __half22float2(*reinterpret_cast<__half2*>(&r1.w));
            A1[0] = fmaf(w1, a.x, A1[0]); A1[1] = fmaf(w1, a.y, A1[1]);
            A1[2] = fmaf(w1, c.x, A1[2]); A1[3] = fmaf(w1, c.y, A1[3]);
            A1[4] = fmaf(w1, d.x, A1[4]); A1[5] = fmaf(w1, d.y, A1[5]);
            A1[6] = fmaf(w1, e.x, A1[6]); A1[7] = fmaf(w1, e.y, A1[7]);
        }
        {
            float2 a = __half22float2(*reinterpret_cast<__half2*>(&r2.x));
            float2 c = __half22float2(*reinterpret_cast<__half2*>(&r2.y));
            float2 d = __half22float2(*reinterpret_cast<__half2*>(&r2.z));
            float2 e = __half22float2(*reinterpret_cast<__half2*>(&r2.w));
            A2[0] = fmaf(w2, a.x, A2[0]); A2[1] = fmaf(w2, a.y, A2[1]);
            A2[2] = fmaf(w2, c.x, A2[2]); A2[3] = fmaf(w2, c.y, A2[3]);
            A2[4] = fmaf(w2, d.x, A2[4]); A2[5] = fmaf(w2, d.y, A2[5]);
            A2[6] = fmaf(w2, e.x, A2[6]); A2[7] = fmaf(w2, e.y, A2[7]);
        }
        {
            float2 a = __half22float2(*reinterpret_cast<__half2*>(&r3.x));
            float2 c = __half22float2(*reinterpret_cast<__half2*>(&r3.y));
            float2 d = __half22float2(*reinterpret_cast<__half2*>(&r3.z));
            float2 e = __half22float2(*reinterpret_cast<__half2*>(&r3.w));
            A3[0] = fmaf(w3, a.x, A3[0]); A3[1] = fmaf(w3, a.y, A3[1]);
            A3[2] = fmaf(w3, c.x, A3[2]); A3[3] = fmaf(w3, c.y, A3[3]);
            A3[4] = fmaf(w3, d.x, A3[4]); A3[5] = fmaf(w3, d.y, A3[5]);
            A3[6] = fmaf(w3, e.x, A3[6]); A3[7] = fmaf(w3, e.y, A3[7]);
        }
    }
    // 16-edge (2-deep)
    for (; j + 16 <= n; j += 16) {
        uint2 p0 = b[j + eg];
        uint2 p1 = b[j + 8 + eg];
        uint4 r0 = *reinterpret_cast<const uint4*>(hp + (size_t)p0.x * 64);
        uint4 r1 = *reinterpret_cast<const uint4*>(hp + (size_t)p1.x * 64);
        float w0 = __uint_as_float(p0.y);
        float w1 = __uint_as_float(p1.y);
        {
            float2 a = __half22float2(*reinterpret_cast<__half2*>(&r0.x));
            float2 c = __half22float2(*reinterpret_cast<__half2*>(&r0.y));
            float2 d = __half22float2(*reinterpret_cast<__half2*>(&r0.z));
            float2 e = __half22float2(*reinterpret_cast<__half2*>(&r0.w));
            A0[0] = fmaf(w0, a.x, A0[0]); A0[1] = fmaf(w0, a.y, A0[1]);
            A0[2] = fmaf(w0, c.x, A0[2]); A0[3] = fmaf(w0, c.y, A0[3]);
            A0[4] = fmaf(w0, d.x, A0[4]); A0[5] = fmaf(w0, d.y, A0[5]);
            A0[6] = fmaf(w0, e.x, A0[6]); A0[7] = fmaf(w0, e.y, A0[7]);
        }
        {
            float2 a = __half22float2(*reinterpret_cast<__half2*>(&r1.x));
            float2 c = __half22float2(*reinterpret_cast<__half2*>(&r1.y));
            float2 d = __half22float2(*reinterpret_cast<__half2*>(&r1.z));
            float2 e = __half22float2(*reinterpret_cast<__half2*>(&r1.w));
            A1[0] = fmaf(w1, a.x, A1[0]); A1[1] = fmaf(w1, a.y, A1[1]);
            A1[2] = fmaf(w1, c.x, A1[2]); A1[3] = fmaf(w1, c.y, A1[3]);
            A1[4] = fmaf(w1, d.x, A1[4]); A1[5] = fmaf(w1, d.y, A1[5]);
            A1[6] = fmaf(w1, e.x, A1[6]); A1[7] = fmaf(w1, e.y, A1[7]);
        }
    }
    // predicated 8-edge tail
    for (; j < n; j += 8) {
        int idx = j + eg;
        uint2 p = (idx < n) ? b[idx] : make_uint2(0u, 0u);  // w=0 for pad lanes
        uint4 r = *reinterpret_cast<const uint4*>(hp + (size_t)p.x * 64);
        float w = __uint_as_float(p.y);
        float2 a = __half22float2(*reinterpret_cast<__half2*>(&r.x));
        float2 c = __half22float2(*reinterpret_cast<__half2*>(&r.y));
        float2 d = __half22float2(*reinterpret_cast<__half2*>(&r.z));
        float2 e = __half22float2(*reinterpret_cast<__half2*>(&r.w));
        A0[0] = fmaf(w, a.x, A0[0]); A0[1] = fmaf(w, a.y, A0[1]);
        A0[2] = fmaf(w, c.x, A0[2]); A0[3] = fmaf(w, c.y, A0[3]);
        A0[4] = fmaf(w, d.x, A0[4]); A0[5] = fmaf(w, d.y, A0[5]);
        A0[6] = fmaf(w, e.x, A0[6]); A0[7] = fmaf(w, e.y, A0[7]);
    }

    float h[8];
    #pragma unroll
    for (int i = 0; i < 8; ++i) {
        float a = (A0[i] + A1[i]) + (A2[i] + A3[i]);
        a += __shfl_xor(a, 8);
        a += __shfl_xor(a, 16);
        a += __shfl_xor(a, 32);
        h[i] = a;
    }
    const float4 bv0 = *reinterpret_cast<const float4*>(bias + fb);
    const float4 bv1 = *reinterpret_cast<const float4*>(bias + fb + 4);
    h[0] = fmaxf(fmaf(h[0], dc, bv0.x), 0.0f);
    h[1] = fmaxf(fmaf(h[1], dc, bv0.y), 0.0f);
    h[2] = fmaxf(fmaf(h[2], dc, bv0.z), 0.0f);
    h[3] = fmaxf(fmaf(h[3], dc, bv0.w), 0.0f);
    h[4] = fmaxf(fmaf(h[4], dc, bv1.x), 0.0f);
    h[5] = fmaxf(fmaf(h[5], dc, bv1.y), 0.0f);
    h[6] = fmaxf(fmaf(h[6], dc, bv1.z), 0.0f);
    h[7] = fmaxf(fmaf(h[7], dc, bv1.w), 0.0f);
    if (FUSE_SCORE) {
        const float4 pv0 = *reinterpret_cast<const float4*>(pw + fb);
        const float4 pv1 = *reinterpret_cast<const float4*>(pw + fb + 4);
        float t = h[0] * pv0.x + h[1] * pv0.y + h[2] * pv0.z + h[3] * pv0.w
                + h[4] * pv1.x + h[5] * pv1.y + h[6] * pv1.z + h[7] * pv1.w;
        #pragma unroll
        for (int m = 1; m <= 4; m <<= 1) t += __shfl_xor(t, m);  // 8-lane group
        float s = 1.0f / (1.0f + expf(-(t + pb[0])));
        #pragma unroll
        for (int i = 0; i < 8; ++i) h[i] *= s;
    }
    if (FUSE_W2) {
        // lane q (0..7) holds hB[8q..8q+7]; out[lane] = dis*sum_k hB[k]*W2[k][lane]
        float a2 = 0.0f;
        #pragma unroll
        for (int q = 0; q < 8; ++q) {
            #pragma unroll
            for (int i = 0; i < 8; ++i) {
                float bq = __shfl(h[i], q);
                a2 = fmaf(bq, W2[(8 * q + i) * 64 + lane], a2);
            }
        }
        Hout[(size_t)wid * 64 + lane] = __float2half(dc * a2);  // coalesced 2B/lane
    } else {
        if (eg == 0) {
            uint4 u;
            __half2 a = __floats2half2_rn(h[0], h[1]);
            __half2 c = __floats2half2_rn(h[2], h[3]);
            __half2 d = __floats2half2_rn(h[4], h[5]);
            __half2 e = __floats2half2_rn(h[6], h[7]);
            u.x = *reinterpret_cast<unsigned*>(&a);
            u.y = *reinterpret_cast<unsigned*>(&c);
            u.z = *reinterpret_cast<unsigned*>(&d);
            u.w = *reinterpret_cast<unsigned*>(&e);
            *reinterpret_cast<uint4*>(Hout + (size_t)wid * 64 + fb) = u;
        }
    }
}

// ---- per-graph max || mean pooling (batch sorted, fp16 input) --------------
__global__ void tpn_pool(const __half* __restrict__ Hs, const int* __restrict__ batch,
                         int N, float* __restrict__ Gf) {
    int g = blockIdx.x;
    int s, e;
    {
        int lo = 0, hi = N;
        while (lo < hi) { int mid = (lo + hi) >> 1; if (batch[mid] < g) lo = mid + 1; else hi = mid; }
        s = lo;
        lo = 0; hi = N;
        while (lo < hi) { int mid = (lo + hi) >> 1; if (batch[mid] < g + 1) lo = mid + 1; else hi = mid; }
        e = lo;
    }
    int lane = threadIdx.x & 63;
    int w = threadIdx.x >> 6;  // 0..3
    float mx = -3.4e38f, sm = 0.0f;
    for (int i = s + w; i < e; i += 4) {
        float v = __half2float(Hs[(size_t)i * 64 + lane]);
        mx = fmaxf(mx, v);
        sm += v;
    }
    __shared__ float shm[4][64], shs[4][64];
    shm[w][lane] = mx; shs[w][lane] = sm;
    __syncthreads();
    if (w == 0) {
        mx = fmaxf(fmaxf(shm[0][lane], shm[1][lane]), fmaxf(shm[2][lane], shm[3][lane]));
        sm = shs[0][lane] + shs[1][lane] + shs[2][lane] + shs[3][lane];
        float c = (float)(e - s);
        float inv = 1.0f / fmaxf(c, 1.0f);
        Gf[g * 128 + lane]      = mx;
        Gf[g * 128 + 64 + lane] = sm * inv;
    }
}

// ---- final MLP: out = relu(G @ lw1 + lb1) @ lw2 + lb2 ----------------------
__global__ void tpn_mlp(const float* __restrict__ Gf, const float* __restrict__ lw1,
                        const float* __restrict__ lb1, const float* __restrict__ lw2,
                        const float* __restrict__ lb2, float* __restrict__ out,
                        int G, int C) {
    int wid = (blockIdx.x * blockDim.x + threadIdx.x) >> 6;
    int lane = threadIdx.x & 63;
    if (wid >= G) return;
    const float* gr = Gf + (size_t)wid * 128;
    float acc = lb1[lane];
    for (int k = 0; k < 128; k += 4) {
        float4 gv = *reinterpret_cast<const float4*>(gr + k);
        acc = fmaf(gv.x, lw1[(k + 0) * 64 + lane], acc);
        acc = fmaf(gv.y, lw1[(k + 1) * 64 + lane], acc);
        acc = fmaf(gv.z, lw1[(k + 2) * 64 + lane], acc);
        acc = fmaf(gv.w, lw1[(k + 3) * 64 + lane], acc);
    }
    float t = fmaxf(acc, 0.0f);
    for (int c = 0; c < C; ++c) {
        float v = t * lw2[lane * C + c];
        #pragma unroll
        for (int m = 32; m > 0; m >>= 1) v += __shfl_xor(v, m);
        if (lane == 0) out[wid * C + c] = v + lb2[c];
    }
}

// ---------------------------------------------------------------------------
extern "C" void kernel_launch(void* const* d_in, const int* in_sizes, int n_in,
                              void* d_out, int out_size, void* d_ws, size_t ws_size,
                              hipStream_t stream) {
    const float* x   = (const float*)d_in[0];
    const int*   ei  = (const int*)  d_in[1];
    const float* ew  = (const float*)d_in[2];
    const int*   bat = (const int*)  d_in[3];
    const float* W1  = (const float*)d_in[5];
    const float* b1  = (const float*)d_in[6];
    const float* W2  = (const float*)d_in[7];
    const float* b2  = (const float*)d_in[8];
    const float* pw  = (const float*)d_in[9];
    const float* pb  = (const float*)d_in[10];
    const float* lw1 = (const float*)d_in[11];
    const float* lb1 = (const float*)d_in[12];
    const float* lw2 = (const float*)d_in[13];
    const float* lb2 = (const float*)d_in[14];
    float* out = (float*)d_out;

    const int N  = in_sizes[3];
    const int E  = in_sizes[2];
    const int IN = in_sizes[0] / N;   // 128
    const int C  = in_sizes[14];      // 2
    const int G  = out_size / C;      // 128
    const int NB = (N + 255) >> 8;    // bins of 256 nodes

    // ---- workspace layout ----
    char* ws = (char*)d_ws;
    size_t o = 0;
    auto alloc = [&](size_t bytes) { void* p = ws + o; o = (o + bytes + 255) & ~(size_t)255; return p; };
    int*   off    = (int*)  alloc((size_t)N * 4);
    int*   cnt    = (int*)  alloc((size_t)N * 4);
    float* dis    = (float*)alloc((size_t)N * 4);
    int*   binCur = (int*)  alloc((size_t)NB_MAX * 4);
    int*   binOff = (int*)  alloc((size_t)NB_MAX * 4);
    float* Gf     = (float*)alloc((size_t)G * 128 * 4);
    uint2* packed = (uint2*)alloc((size_t)E * 8);
    // shared region: binned (NB*BCAP*8 = 38.4MB) overlays hA+hB (25.6MB);
    // binned dead after tpn_build.
    size_t binned_bytes = (size_t)NB * BCAP * 8;
    size_t act_bytes    = (size_t)N * 64 * 2 * 2;
    char*  region = (char*)alloc(binned_bytes > act_bytes ? binned_bytes : act_bytes);
    uint2* binned = (uint2*)region;
    __half* hA = (__half*)region;
    __half* hB = (__half*)(region + (size_t)N * 64 * 2);
    (void)n_in; (void)ws_size;

    (void)hipMemsetAsync(binCur, 0, (size_t)NB_MAX * 4, stream);

    const int p1b   = (E + P1_CHUNK - 1) / P1_CHUNK;
    const int ggrid = (N + 63) / 64;                        // gemm tiles
    const int agrid = (N * 64 + TPN_BLK - 1) / TPN_BLK;     // wave per node

    // CSR build: bin (LDS sort, coalesced) -> scan -> build
    tpn_bin<<<p1b, TPN_BLK, 0, stream>>>(ei, ew, binCur, binned, E, NB);
    tpn_binscan<<<1, NB_MAX, 0, stream>>>(binCur, binOff, NB);
    tpn_build<<<NB, 256, 0, stream>>>(binned, binCur, binOff, packed, off, cnt, dis, N);

    // layer 1 (+fused gemm2): hA = fp16(dis*(x@W1));
    //                         hB = fp16(dis*(relu(dis*agg(hA)+b1)@W2))
    tpn_gemm_t<<<ggrid, 256, 0, stream>>>(x, W1, dis, hA, N, IN);
    tpn_agg<false, true><<<agrid, TPN_BLK, 0, stream>>>(packed, off, cnt, dis, hA,
                                                        b1, pw, pb, W2, hB, N);

    // layer 2: hA = fp16(score-gated relu(dis*agg(hB) + b2))
    tpn_agg<true, false><<<agrid, TPN_BLK, 0, stream>>>(packed, off, cnt, dis, hB,
                                                        b2, pw, pb, W2, hA, N);

    // pooling + MLP head
    tpn_pool<<<G, TPN_BLK, 0, stream>>>(hA, bat, N, Gf);
    tpn_mlp<<<(G * 64 + TPN_BLK - 1) / TPN_BLK, TPN_BLK, 0, stream>>>(Gf, lw1, lb1, lw2, lb2, out, G, C);
}

// Round 20
// 346.592 us; speedup vs baseline: 1.0691x; 1.0691x over previous
//
#include <hip/hip_runtime.h>
#include <hip/hip_fp16.h>
#include <math.h>

// ---------------------------------------------------------------------------
// TopoPoolNet: GCN(128->64) -> GCN(64->64) -> sigmoid score gate ->
//              per-graph max||mean pool -> MLP(128->64->2)
//
// Round-19: revert to the best measured configuration (R17, 347us).
// R18's 4-deep unroll crossed a VGPR/occupancy step (80%->50%) and regressed.
// Final structure: LDS counting-sort CSR build; tiled GEMM1 (+dis folded);
// agg = wave/node, 8 lanes x dwordx4 fp16 rows, 2 indep chains, fused W2
// (layer1) and sigmoid gate (layer2); fp16 activations, fp32 math.
// Agg pinned at ~110us across 9 structural variants (no saturated counter;
// random-gather latency/request floor). FETCH ~164MB ~= analytic floor.
// ---------------------------------------------------------------------------

#define TPN_BLK 256
#define P1_EPT  16                   // edges per thread in bin pass
#define P1_CHUNK (TPN_BLK * P1_EPT)  // 4096 edges per block
#define NB_MAX  512
#define BCAP    12288                // per-bin capacity (mean ~8184)

static __device__ __forceinline__ uint2 f4_to_h4(float4 v) {
    __half2 a = __floats2half2_rn(v.x, v.y);
    __half2 b = __floats2half2_rn(v.z, v.w);
    uint2 u;
    u.x = *reinterpret_cast<unsigned*>(&a);
    u.y = *reinterpret_cast<unsigned*>(&b);
    return u;
}

// ---- pass 1: block-level counting sort by bin (col>>8), coalesced out -----
__global__ __launch_bounds__(256)
void tpn_bin(const int* __restrict__ ei, const float* __restrict__ ew,
             int* __restrict__ binCur, uint2* __restrict__ binned,
             int E, int NB) {
    __shared__ uint2          sbuf[P1_CHUNK];      // 32 KB
    __shared__ unsigned short sbin[P1_CHUNK];      // 8 KB
    __shared__ int hist[NB_MAX];
    __shared__ int loff[NB_MAX];
    __shared__ int lrank[NB_MAX];
    __shared__ int gbase[NB_MAX];
    __shared__ int ssc[256];

    int tid = threadIdx.x;
    for (int b = tid; b < NB_MAX; b += 256) { hist[b] = 0; lrank[b] = 0; }
    __syncthreads();

    int base = blockIdx.x * P1_CHUNK;
    uint2 ed[P1_EPT];
    int   bn[P1_EPT];
    #pragma unroll
    for (int j = 0; j < P1_EPT; ++j) {
        int e = base + tid + j * 256;
        bn[j] = -1;
        if (e < E) {
            int r = ei[e], c = ei[E + e];
            bn[j] = c >> 8;
            ed[j] = make_uint2((unsigned)r | ((unsigned)(c & 255) << 17),
                               __float_as_uint(ew[e]));
            atomicAdd(&hist[bn[j]], 1);
        }
    }
    __syncthreads();
    {
        int b0 = 2 * tid, b1 = 2 * tid + 1;
        int h0 = hist[b0], h1 = hist[b1];
        int s = h0 + h1;
        ssc[tid] = s;
        __syncthreads();
        for (int st = 1; st < 256; st <<= 1) {
            int v = (tid >= st) ? ssc[tid - st] : 0;
            __syncthreads();
            ssc[tid] += v;
            __syncthreads();
        }
        int pre = ssc[tid] - s;
        loff[b0] = pre;
        loff[b1] = pre + h0;
    }
    __syncthreads();
    for (int b = tid; b < NB; b += 256) {
        int h = hist[b];
        if (h > 0) gbase[b] = atomicAdd(&binCur[b], h);
    }
    #pragma unroll
    for (int j = 0; j < P1_EPT; ++j) {
        if (bn[j] >= 0) {
            int p = loff[bn[j]] + atomicAdd(&lrank[bn[j]], 1);
            sbuf[p] = ed[j];
            sbin[p] = (unsigned short)bn[j];
        }
    }
    __syncthreads();
    int m = min(E - base, P1_CHUNK);
    for (int i = tid; i < m; i += 256) {
        uint2 u = sbuf[i];
        int b = sbin[i];
        int dst = gbase[b] + (i - loff[b]);
        if (dst < BCAP) binned[(size_t)b * BCAP + dst] = u;
    }
}

// ---- exclusive scan of bin counts (single block) ---------------------------
__global__ void tpn_binscan(const int* __restrict__ binCur, int* __restrict__ binOff,
                            int NB) {
    __shared__ int sh[NB_MAX];
    int t = threadIdx.x;
    int v = (t < NB) ? min(binCur[t], BCAP) : 0;
    sh[t] = v;
    __syncthreads();
    for (int st = 1; st < NB_MAX; st <<= 1) {
        int u = (t >= st) ? sh[t - st] : 0;
        __syncthreads();
        sh[t] += u;
        __syncthreads();
    }
    if (t < NB) binOff[t] = sh[t] - v;
}

// ---- pass 2: per-bin packed CSR build + dis --------------------------------
__global__ void tpn_build(const uint2* __restrict__ binned, const int* __restrict__ binCur,
                          const int* __restrict__ binOff, uint2* __restrict__ packed,
                          int* __restrict__ off, int* __restrict__ cnt,
                          float* __restrict__ dis, int N) {
    __shared__ int   lcnt[256];
    __shared__ int   loff[256];
    __shared__ int   lrank[256];
    __shared__ int   lincl[256];
    __shared__ float ldeg[256];
    int b = blockIdx.x, tid = threadIdx.x;
    int m = min(binCur[b], BCAP);
    const uint2* src = binned + (size_t)b * BCAP;
    lcnt[tid] = 0; lrank[tid] = 0; ldeg[tid] = 0.0f;
    __syncthreads();
    for (int i = tid; i < m; i += 256) {
        uint2 u = src[i];
        int ln = u.x >> 17;
        atomicAdd(&lcnt[ln], 1);
        atomicAdd(&ldeg[ln], __uint_as_float(u.y));
    }
    __syncthreads();
    lincl[tid] = lcnt[tid];
    __syncthreads();
    for (int st = 1; st < 256; st <<= 1) {
        int u = (tid >= st) ? lincl[tid - st] : 0;
        __syncthreads();
        lincl[tid] += u;
        __syncthreads();
    }
    int excl = lincl[tid] - lcnt[tid];
    loff[tid] = excl;
    int node = (b << 8) + tid;
    if (node < N) {
        off[node] = binOff[b] + excl;
        cnt[node] = lcnt[tid];
        float s = ldeg[tid];
        dis[node] = (s > 0.0f) ? rsqrtf(fmaxf(s, 1e-12f)) : 0.0f;
    }
    __syncthreads();
    int gbase = binOff[b];
    for (int i = tid; i < m; i += 256) {
        uint2 u = src[i];
        int ln = u.x >> 17;
        int rk = atomicAdd(&lrank[ln], 1);
        packed[gbase + loff[ln] + rk] = make_uint2(u.x & 0x1FFFF, u.y);
    }
}

// ---- tiled GEMM: Y[n,f] = fp16(dis[n] * sum_k X[n,k]*W[k,f]); 64x64 tile ---
__global__ __launch_bounds__(256, 4)
void tpn_gemm_t(const float* __restrict__ X, const float* __restrict__ W,
                const float* __restrict__ dis, __half* __restrict__ Y,
                int N, int K) {
    __shared__ float sX[64][68];
    __shared__ float sW[64][64];
    const int t  = threadIdx.x;
    const int r  = t >> 4;
    const int cc = t & 15;
    const int fg = t & 15;
    const int ng = t >> 4;
    const int nb = blockIdx.x * 64;

    float acc[4][4] = {{0.f}};

    for (int kc = 0; kc < K; kc += 64) {
        __syncthreads();
        #pragma unroll
        for (int p = 0; p < 4; ++p) {
            int n = nb + r + p * 16;
            int ns = (n < N) ? n : (N - 1);
            float4 v = *reinterpret_cast<const float4*>(X + (size_t)ns * K + kc + 4 * cc);
            *reinterpret_cast<float4*>(&sX[r + p * 16][4 * cc]) = v;
        }
        #pragma unroll
        for (int p = 0; p < 4; ++p) {
            int k = kc + r + p * 16;
            float4 v = *reinterpret_cast<const float4*>(W + (size_t)k * 64 + 4 * cc);
            *reinterpret_cast<float4*>(&sW[r + p * 16][4 * cc]) = v;
        }
        __syncthreads();
        #pragma unroll 4
        for (int k = 0; k < 64; ++k) {
            float4 wv = *reinterpret_cast<const float4*>(&sW[k][4 * fg]);
            float x0 = sX[4 * ng + 0][k];
            float x1 = sX[4 * ng + 1][k];
            float x2 = sX[4 * ng + 2][k];
            float x3 = sX[4 * ng + 3][k];
            acc[0][0] = fmaf(x0, wv.x, acc[0][0]);
            acc[0][1] = fmaf(x0, wv.y, acc[0][1]);
            acc[0][2] = fmaf(x0, wv.z, acc[0][2]);
            acc[0][3] = fmaf(x0, wv.w, acc[0][3]);
            acc[1][0] = fmaf(x1, wv.x, acc[1][0]);
            acc[1][1] = fmaf(x1, wv.y, acc[1][1]);
            acc[1][2] = fmaf(x1, wv.z, acc[1][2]);
            acc[1][3] = fmaf(x1, wv.w, acc[1][3]);
            acc[2][0] = fmaf(x2, wv.x, acc[2][0]);
            acc[2][1] = fmaf(x2, wv.y, acc[2][1]);
            acc[2][2] = fmaf(x2, wv.z, acc[2][2]);
            acc[2][3] = fmaf(x2, wv.w, acc[2][3]);
            acc[3][0] = fmaf(x3, wv.x, acc[3][0]);
            acc[3][1] = fmaf(x3, wv.y, acc[3][1]);
            acc[3][2] = fmaf(x3, wv.z, acc[3][2]);
            acc[3][3] = fmaf(x3, wv.w, acc[3][3]);
        }
    }
    #pragma unroll
    for (int i = 0; i < 4; ++i) {
        int n = nb + 4 * ng + i;
        if (n < N) {
            float d = dis[n];
            float4 v = make_float4(acc[i][0] * d, acc[i][1] * d,
                                   acc[i][2] * d, acc[i][3] * d);
            *reinterpret_cast<uint2*>(Y + (size_t)n * 64 + 4 * fg) = f4_to_h4(v);
        }
    }
}

// ---- aggregate: wave/node, 8 lanes x dwordx4 (16B) per edge row ------------
// 8 edge slots/wave, 2 unrolled passes -> 16 rows in flight, 8 addr/row.
// FUSE_W2: epilogue computes Hout_row = fp16(dis[n] * (relu_row @ W2)).
// FUSE_SCORE: sigmoid score gate (layer 2).
template <bool FUSE_SCORE, bool FUSE_W2>
__global__ __launch_bounds__(256)
void tpn_agg(const uint2* __restrict__ packed, const int* __restrict__ off,
             const int* __restrict__ cnt, const float* __restrict__ dis,
             const __half* __restrict__ Hin, const float* __restrict__ bias,
             const float* __restrict__ pw, const float* __restrict__ pb,
             const float* __restrict__ W2, __half* __restrict__ Hout, int N) {
    int wid = (blockIdx.x * blockDim.x + threadIdx.x) >> 6;
    int lane = threadIdx.x & 63;
    if (wid >= N) return;
    const int eg = lane >> 3;        // edge slot 0..7
    const int fb = (lane & 7) * 8;   // feature base: fb..fb+7 (8 fp16 = 16B)
    int start = off[wid], n = cnt[wid];
    const uint2* b = packed + start;
    const __half* hp = Hin + fb;
    float dc = dis[wid];

    float A0[8], A1[8];
    #pragma unroll
    for (int i = 0; i < 8; ++i) { A0[i] = 0.f; A1[i] = 0.f; }

    int j = 0;
    for (; j + 16 <= n; j += 16) {
        uint2 p0 = b[j + eg];
        uint2 p1 = b[j + 8 + eg];
        uint4 r0 = *reinterpret_cast<const uint4*>(hp + (size_t)p0.x * 64);
        uint4 r1 = *reinterpret_cast<const uint4*>(hp + (size_t)p1.x * 64);
        float w0 = __uint_as_float(p0.y);
        float w1 = __uint_as_float(p1.y);
        {
            float2 a = __half22float2(*reinterpret_cast<__half2*>(&r0.x));
            float2 c = __half22float2(*reinterpret_cast<__half2*>(&r0.y));
            float2 d = __half22float2(*reinterpret_cast<__half2*>(&r0.z));
            float2 e = __half22float2(*reinterpret_cast<__half2*>(&r0.w));
            A0[0] = fmaf(w0, a.x, A0[0]); A0[1] = fmaf(w0, a.y, A0[1]);
            A0[2] = fmaf(w0, c.x, A0[2]); A0[3] = fmaf(w0, c.y, A0[3]);
            A0[4] = fmaf(w0, d.x, A0[4]); A0[5] = fmaf(w0, d.y, A0[5]);
            A0[6] = fmaf(w0, e.x, A0[6]); A0[7] = fmaf(w0, e.y, A0[7]);
        }
        {
            float2 a = __half22float2(*reinterpret_cast<__half2*>(&r1.x));
            float2 c = __half22float2(*reinterpret_cast<__half2*>(&r1.y));
            float2 d = __half22float2(*reinterpret_cast<__half2*>(&r1.z));
            float2 e = __half22float2(*reinterpret_cast<__half2*>(&r1.w));
            A1[0] = fmaf(w1, a.x, A1[0]); A1[1] = fmaf(w1, a.y, A1[1]);
            A1[2] = fmaf(w1, c.x, A1[2]); A1[3] = fmaf(w1, c.y, A1[3]);
            A1[4] = fmaf(w1, d.x, A1[4]); A1[5] = fmaf(w1, d.y, A1[5]);
            A1[6] = fmaf(w1, e.x, A1[6]); A1[7] = fmaf(w1, e.y, A1[7]);
        }
    }
    for (; j < n; j += 8) {
        int idx = j + eg;
        uint2 p = (idx < n) ? b[idx] : make_uint2(0u, 0u);  // w=0 for pad lanes
        uint4 r = *reinterpret_cast<const uint4*>(hp + (size_t)p.x * 64);
        float w = __uint_as_float(p.y);
        float2 a = __half22float2(*reinterpret_cast<__half2*>(&r.x));
        float2 c = __half22float2(*reinterpret_cast<__half2*>(&r.y));
        float2 d = __half22float2(*reinterpret_cast<__half2*>(&r.z));
        float2 e = __half22float2(*reinterpret_cast<__half2*>(&r.w));
        A0[0] = fmaf(w, a.x, A0[0]); A0[1] = fmaf(w, a.y, A0[1]);
        A0[2] = fmaf(w, c.x, A0[2]); A0[3] = fmaf(w, c.y, A0[3]);
        A0[4] = fmaf(w, d.x, A0[4]); A0[5] = fmaf(w, d.y, A0[5]);
        A0[6] = fmaf(w, e.x, A0[6]); A0[7] = fmaf(w, e.y, A0[7]);
    }

    float h[8];
    #pragma unroll
    for (int i = 0; i < 8; ++i) {
        float a = A0[i] + A1[i];
        a += __shfl_xor(a, 8);
        a += __shfl_xor(a, 16);
        a += __shfl_xor(a, 32);
        h[i] = a;
    }
    const float4 bv0 = *reinterpret_cast<const float4*>(bias + fb);
    const float4 bv1 = *reinterpret_cast<const float4*>(bias + fb + 4);
    h[0] = fmaxf(fmaf(h[0], dc, bv0.x), 0.0f);
    h[1] = fmaxf(fmaf(h[1], dc, bv0.y), 0.0f);
    h[2] = fmaxf(fmaf(h[2], dc, bv0.z), 0.0f);
    h[3] = fmaxf(fmaf(h[3], dc, bv0.w), 0.0f);
    h[4] = fmaxf(fmaf(h[4], dc, bv1.x), 0.0f);
    h[5] = fmaxf(fmaf(h[5], dc, bv1.y), 0.0f);
    h[6] = fmaxf(fmaf(h[6], dc, bv1.z), 0.0f);
    h[7] = fmaxf(fmaf(h[7], dc, bv1.w), 0.0f);
    if (FUSE_SCORE) {
        const float4 pv0 = *reinterpret_cast<const float4*>(pw + fb);
        const float4 pv1 = *reinterpret_cast<const float4*>(pw + fb + 4);
        float t = h[0] * pv0.x + h[1] * pv0.y + h[2] * pv0.z + h[3] * pv0.w
                + h[4] * pv1.x + h[5] * pv1.y + h[6] * pv1.z + h[7] * pv1.w;
        #pragma unroll
        for (int m = 1; m <= 4; m <<= 1) t += __shfl_xor(t, m);  // 8-lane group
        float s = 1.0f / (1.0f + expf(-(t + pb[0])));
        #pragma unroll
        for (int i = 0; i < 8; ++i) h[i] *= s;
    }
    if (FUSE_W2) {
        // lane q (0..7) holds hB[8q..8q+7]; out[lane] = dis*sum_k hB[k]*W2[k][lane]
        float a2 = 0.0f;
        #pragma unroll
        for (int q = 0; q < 8; ++q) {
            #pragma unroll
            for (int i = 0; i < 8; ++i) {
                float bq = __shfl(h[i], q);
                a2 = fmaf(bq, W2[(8 * q + i) * 64 + lane], a2);
            }
        }
        Hout[(size_t)wid * 64 + lane] = __float2half(dc * a2);  // coalesced 2B/lane
    } else {
        if (eg == 0) {
            uint4 u;
            __half2 a = __floats2half2_rn(h[0], h[1]);
            __half2 c = __floats2half2_rn(h[2], h[3]);
            __half2 d = __floats2half2_rn(h[4], h[5]);
            __half2 e = __floats2half2_rn(h[6], h[7]);
            u.x = *reinterpret_cast<unsigned*>(&a);
            u.y = *reinterpret_cast<unsigned*>(&c);
            u.z = *reinterpret_cast<unsigned*>(&d);
            u.w = *reinterpret_cast<unsigned*>(&e);
            *reinterpret_cast<uint4*>(Hout + (size_t)wid * 64 + fb) = u;
        }
    }
}

// ---- per-graph max || mean pooling (batch sorted, fp16 input) --------------
__global__ void tpn_pool(const __half* __restrict__ Hs, const int* __restrict__ batch,
                         int N, float* __restrict__ Gf) {
    int g = blockIdx.x;
    int s, e;
    {
        int lo = 0, hi = N;
        while (lo < hi) { int mid = (lo + hi) >> 1; if (batch[mid] < g) lo = mid + 1; else hi = mid; }
        s = lo;
        lo = 0; hi = N;
        while (lo < hi) { int mid = (lo + hi) >> 1; if (batch[mid] < g + 1) lo = mid + 1; else hi = mid; }
        e = lo;
    }
    int lane = threadIdx.x & 63;
    int w = threadIdx.x >> 6;  // 0..3
    float mx = -3.4e38f, sm = 0.0f;
    for (int i = s + w; i < e; i += 4) {
        float v = __half2float(Hs[(size_t)i * 64 + lane]);
        mx = fmaxf(mx, v);
        sm += v;
    }
    __shared__ float shm[4][64], shs[4][64];
    shm[w][lane] = mx; shs[w][lane] = sm;
    __syncthreads();
    if (w == 0) {
        mx = fmaxf(fmaxf(shm[0][lane], shm[1][lane]), fmaxf(shm[2][lane], shm[3][lane]));
        sm = shs[0][lane] + shs[1][lane] + shs[2][lane] + shs[3][lane];
        float c = (float)(e - s);
        float inv = 1.0f / fmaxf(c, 1.0f);
        Gf[g * 128 + lane]      = mx;
        Gf[g * 128 + 64 + lane] = sm * inv;
    }
}

// ---- final MLP: out = relu(G @ lw1 + lb1) @ lw2 + lb2 ----------------------
__global__ void tpn_mlp(const float* __restrict__ Gf, const float* __restrict__ lw1,
                        const float* __restrict__ lb1, const float* __restrict__ lw2,
                        const float* __restrict__ lb2, float* __restrict__ out,
                        int G, int C) {
    int wid = (blockIdx.x * blockDim.x + threadIdx.x) >> 6;
    int lane = threadIdx.x & 63;
    if (wid >= G) return;
    const float* gr = Gf + (size_t)wid * 128;
    float acc = lb1[lane];
    for (int k = 0; k < 128; k += 4) {
        float4 gv = *reinterpret_cast<const float4*>(gr + k);
        acc = fmaf(gv.x, lw1[(k + 0) * 64 + lane], acc);
        acc = fmaf(gv.y, lw1[(k + 1) * 64 + lane], acc);
        acc = fmaf(gv.z, lw1[(k + 2) * 64 + lane], acc);
        acc = fmaf(gv.w, lw1[(k + 3) * 64 + lane], acc);
    }
    float t = fmaxf(acc, 0.0f);
    for (int c = 0; c < C; ++c) {
        float v = t * lw2[lane * C + c];
        #pragma unroll
        for (int m = 32; m > 0; m >>= 1) v += __shfl_xor(v, m);
        if (lane == 0) out[wid * C + c] = v + lb2[c];
    }
}

// ---------------------------------------------------------------------------
extern "C" void kernel_launch(void* const* d_in, const int* in_sizes, int n_in,
                              void* d_out, int out_size, void* d_ws, size_t ws_size,
                              hipStream_t stream) {
    const float* x   = (const float*)d_in[0];
    const int*   ei  = (const int*)  d_in[1];
    const float* ew  = (const float*)d_in[2];
    const int*   bat = (const int*)  d_in[3];
    const float* W1  = (const float*)d_in[5];
    const float* b1  = (const float*)d_in[6];
    const float* W2  = (const float*)d_in[7];
    const float* b2  = (const float*)d_in[8];
    const float* pw  = (const float*)d_in[9];
    const float* pb  = (const float*)d_in[10];
    const float* lw1 = (const float*)d_in[11];
    const float* lb1 = (const float*)d_in[12];
    const float* lw2 = (const float*)d_in[13];
    const float* lb2 = (const float*)d_in[14];
    float* out = (float*)d_out;

    const int N  = in_sizes[3];
    const int E  = in_sizes[2];
    const int IN = in_sizes[0] / N;   // 128
    const int C  = in_sizes[14];      // 2
    const int G  = out_size / C;      // 128
    const int NB = (N + 255) >> 8;    // bins of 256 nodes

    // ---- workspace layout ----
    char* ws = (char*)d_ws;
    size_t o = 0;
    auto alloc = [&](size_t bytes) { void* p = ws + o; o = (o + bytes + 255) & ~(size_t)255; return p; };
    int*   off    = (int*)  alloc((size_t)N * 4);
    int*   cnt    = (int*)  alloc((size_t)N * 4);
    float* dis    = (float*)alloc((size_t)N * 4);
    int*   binCur = (int*)  alloc((size_t)NB_MAX * 4);
    int*   binOff = (int*)  alloc((size_t)NB_MAX * 4);
    float* Gf     = (float*)alloc((size_t)G * 128 * 4);
    uint2* packed = (uint2*)alloc((size_t)E * 8);
    // shared region: binned (NB*BCAP*8 = 38.4MB) overlays hA+hB (25.6MB);
    // binned dead after tpn_build.
    size_t binned_bytes = (size_t)NB * BCAP * 8;
    size_t act_bytes    = (size_t)N * 64 * 2 * 2;
    char*  region = (char*)alloc(binned_bytes > act_bytes ? binned_bytes : act_bytes);
    uint2* binned = (uint2*)region;
    __half* hA = (__half*)region;
    __half* hB = (__half*)(region + (size_t)N * 64 * 2);
    (void)n_in; (void)ws_size;

    (void)hipMemsetAsync(binCur, 0, (size_t)NB_MAX * 4, stream);

    const int p1b   = (E + P1_CHUNK - 1) / P1_CHUNK;
    const int ggrid = (N + 63) / 64;                        // gemm tiles
    const int agrid = (N * 64 + TPN_BLK - 1) / TPN_BLK;     // wave per node

    // CSR build: bin (LDS sort, coalesced) -> scan -> build
    tpn_bin<<<p1b, TPN_BLK, 0, stream>>>(ei, ew, binCur, binned, E, NB);
    tpn_binscan<<<1, NB_MAX, 0, stream>>>(binCur, binOff, NB);
    tpn_build<<<NB, 256, 0, stream>>>(binned, binCur, binOff, packed, off, cnt, dis, N);

    // layer 1 (+fused gemm2): hA = fp16(dis*(x@W1));
    //                         hB = fp16(dis*(relu(dis*agg(hA)+b1)@W2))
    tpn_gemm_t<<<ggrid, 256, 0, stream>>>(x, W1, dis, hA, N, IN);
    tpn_agg<false, true><<<agrid, TPN_BLK, 0, stream>>>(packed, off, cnt, dis, hA,
                                                        b1, pw, pb, W2, hB, N);

    // layer 2: hA = fp16(score-gated relu(dis*agg(hB) + b2))
    tpn_agg<true, false><<<agrid, TPN_BLK, 0, stream>>>(packed, off, cnt, dis, hB,
                                                        b2, pw, pb, W2, hA, N);

    // pooling + MLP head
    tpn_pool<<<G, TPN_BLK, 0, stream>>>(hA, bat, N, Gf);
    tpn_mlp<<<(G * 64 + TPN_BLK - 1) / TPN_BLK, TPN_BLK, 0, stream>>>(Gf, lw1, lb1, lw2, lb2, out, G, C);
}